// Round 1
// baseline (16.146 us; speedup 1.0000x reference)
//
#include <hip/hip_runtime.h>

// Problem constants (match reference)
constexpr int WIDTH       = 1000;
constexpr int N_PIXELS    = 1000 * 1000;
constexpr int PATCH_SIZE  = 5;
constexpr int PATCHES_X   = WIDTH / PATCH_SIZE;   // 200
constexpr int NUM_TERMS   = 10;

// out[c, n] = sum_t sum_d coeff[patch(n), c, t, d] * pix[n, d]^t + bias[patch(n), c]
__global__ __launch_bounds__(256) void ts_approx_kernel(
    const float* __restrict__ pix,      // [N, 2]
    const float* __restrict__ coef,     // [NUM_PATCHES, 3, 10, 2] -> stride 60 per patch
    const float* __restrict__ bias,     // [NUM_PATCHES, 3]
    float* __restrict__ out)            // [3, N]
{
    int n = blockIdx.x * blockDim.x + threadIdx.x;
    if (n >= N_PIXELS) return;

    float2 p = reinterpret_cast<const float2*>(pix)[n];

    int row = n / WIDTH;
    int col = n - row * WIDTH;
    int patch = (row / PATCH_SIZE) * PATCHES_X + (col / PATCH_SIZE);

    // powers x^t, y^t for t = 0..9
    float xp[NUM_TERMS], yp[NUM_TERMS];
    xp[0] = 1.0f; yp[0] = 1.0f;
    #pragma unroll
    for (int t = 1; t < NUM_TERMS; ++t) {
        xp[t] = xp[t - 1] * p.x;
        yp[t] = yp[t - 1] * p.y;
    }

    const float* cg = coef + (long)patch * 60;
    const float* bg = bias + (long)patch * 3;

    float acc[3];
    #pragma unroll
    for (int c = 0; c < 3; ++c) {
        const float4* c4 = reinterpret_cast<const float4*>(cg + c * 20);
        float a = 0.0f;
        #pragma unroll
        for (int i = 0; i < 5; ++i) {
            // c4[i] = { coeff[t=2i,d=0], coeff[t=2i,d=1], coeff[t=2i+1,d=0], coeff[t=2i+1,d=1] }
            float4 v = c4[i];
            a = fmaf(v.x, xp[2 * i],     a);
            a = fmaf(v.y, yp[2 * i],     a);
            a = fmaf(v.z, xp[2 * i + 1], a);
            a = fmaf(v.w, yp[2 * i + 1], a);
        }
        acc[c] = a + bg[c];
    }

    out[0 * N_PIXELS + n] = acc[0];
    out[1 * N_PIXELS + n] = acc[1];
    out[2 * N_PIXELS + n] = acc[2];
}

extern "C" void kernel_launch(void* const* d_in, const int* in_sizes, int n_in,
                              void* d_out, int out_size, void* d_ws, size_t ws_size,
                              hipStream_t stream) {
    const float* pix  = (const float*)d_in[0];
    const float* coef = (const float*)d_in[1];
    const float* bias = (const float*)d_in[2];
    float* out = (float*)d_out;

    const int block = 256;
    const int grid = (N_PIXELS + block - 1) / block;
    ts_approx_kernel<<<grid, block, 0, stream>>>(pix, coef, bias, out);
}